// Round 10
// baseline (119.260 us; speedup 1.0000x reference)
//
#include <hip/hip_runtime.h>
#include <math.h>

namespace {
constexpr int Bc = 2, Hc = 224, Wc = 224, HWc = Hc * Wc;
constexpr int COUTc = 64, PADc = 3;
constexpr int MIXc = 4, RELc = 32;
constexpr int PHc = 230, PWc = 230;
constexpr int FHc = 112, FWc = 112, NN = FHc * FWc;  // 12544
constexpr int NK = 49;
constexpr int NCHUNK = 196;                          // 64-px chunks (K1)
// ws float offsets
constexpr int WS_EEX = 0;                            // [4][230]
constexpr int WS_EEY = WS_EEX + MIXc * PWc;          // [4][230]
constexpr int WS_PART = WS_EEY + MIXc * PHc;         // [B][49][196]
}

// Collapsed weights into sCol[51]: M[9], Rx[21], Ry[21]. Threads 0..50.
__device__ __forceinline__ void collapse(const float* __restrict__ wq,
                                         const float* __restrict__ wk,
                                         const float* __restrict__ rx,
                                         const float* __restrict__ ry,
                                         float* sCol) {
  const int t = threadIdx.x;
  if (t < 51) {
    float s = 0.f;
    if (t < 9) {
      const int cj = t / 3, ci = t % 3;
#pragma unroll 8
      for (int o = 0; o < COUTc; ++o) s += wq[cj * COUTc + o] * wk[ci * COUTc + o];
    } else if (t < 30) {
      const int v = t - 9, cj = v / 7, kw = v % 7;
#pragma unroll 8
      for (int o = 0; o < RELc; ++o) s += wq[cj * COUTc + o] * rx[o * 7 + kw];
    } else {
      const int v = t - 30, cj = v / 7, kh = v % 7;
#pragma unroll 8
      for (int o = 0; o < RELc; ++o) s += wq[cj * COUTc + RELc + o] * ry[o * 7 + kh];
    }
    sCol[t] = s;
  }
}

// ---- K1: denominator partials (+ mixture tables from 8 blocks).
// grid (196, 13, 2), block 256 = 4 waves; wave w owns k = by*4+w over 64 px.
__global__ __launch_bounds__(256) void sam_stats(
    const float* __restrict__ x, const float* __restrict__ wq,
    const float* __restrict__ wk, const float* __restrict__ rx,
    const float* __restrict__ ry, const float* __restrict__ ex,
    const float* __restrict__ ey, const float* __restrict__ em,
    float* __restrict__ ws) {
  __shared__ float sCol[51];
  const int t = threadIdx.x;
  collapse(wq, wk, rx, ry, sCol);

  // Mixture tables: blocks (bx<8, by==0, bz==0); 8*256 threads cover 1840.
  if (blockIdx.y == 0 && blockIdx.z == 0 && blockIdx.x < 8) {
    const int idx = blockIdx.x * 256 + t;
    constexpr int half = MIXc * PWc;
    if (idx < 2 * half) {
      const int which = idx >= half;
      const int r = which ? idx - half : idx;
      const int m = r / PWc, j = r % PWc;
      float s = 0.f;
#pragma unroll 8
      for (int cc = 0; cc < COUTc; ++cc)
        s += (which ? ey[cc * PHc + j] : ex[cc * PWc + j]) * em[m * COUTc + cc];
      ws[idx] = __expf(s);
    }
  }
  __syncthreads();

  const int w = t >> 6, lane = t & 63;
  const int k = blockIdx.y * 4 + w;
  if (k >= NK) return;
  const int b = blockIdx.z;
  const int kh = k / 7, kw = k - 7 * kh;
  const int n = blockIdx.x * 64 + lane;
  const int fh = n / FWc, fw = n - fh * FWc;
  const int i0 = 2 * fh, j0 = 2 * fw;
  const float* xb = x + (size_t)b * 3 * HWc;
  const int co = i0 * Wc + j0;
  const float xc0 = xb[co], xc1 = xb[HWc + co], xc2 = xb[2 * HWc + co];

  float s = xc0 * (sCol[9 + kw] + sCol[30 + kh]) +
            xc1 * (sCol[16 + kw] + sCol[37 + kh]) +
            xc2 * (sCol[23 + kw] + sCol[44 + kh]);
  const int ir = i0 + kh - PADc, jc = j0 + kw - PADc;
  if ((unsigned)ir < (unsigned)Hc && (unsigned)jc < (unsigned)Wc) {
    const float q0 = xc0 * sCol[0] + xc1 * sCol[3] + xc2 * sCol[6];
    const float q1 = xc0 * sCol[1] + xc1 * sCol[4] + xc2 * sCol[7];
    const float q2 = xc0 * sCol[2] + xc1 * sCol[5] + xc2 * sCol[8];
    const int off = ir * Wc + jc;
    s += q0 * xb[off] + q1 * xb[HWc + off] + q2 * xb[2 * HWc + off];
  }
  float e = __expf(s);
#pragma unroll
  for (int m2 = 32; m2; m2 >>= 1) e += __shfl_xor(e, m2, 64);
  if (lane == 0) ws[WS_PART + (b * NK + k) * NCHUNK + blockIdx.x] = e;
}

// ---- K2: denominators + score recompute + mixture-weighted accumulation.
// grid (392, 2), block 256 = 32 px x 8 tap-groups.
__global__ __launch_bounds__(256) void sam_out(
    const float* __restrict__ x, const float* __restrict__ wq,
    const float* __restrict__ wk, const float* __restrict__ rx,
    const float* __restrict__ ry, const float* __restrict__ wv,
    const float* __restrict__ bias, const float* __restrict__ ws,
    float* __restrict__ out) {
  __shared__ float sCol[51];
  __shared__ float sEEX[MIXc * PWc];
  __shared__ float sEEY[MIXc * PHc];
  __shared__ float sdninv[NK];
  __shared__ float swv[12 * 64];
  __shared__ float sbias[64];
  __shared__ float sT[8][32][13];

  const int t = threadIdx.x;
  const int c = blockIdx.x, b = blockIdx.y;
  collapse(wq, wk, rx, ry, sCol);
  for (int i = t; i < MIXc * PWc; i += 256) sEEX[i] = ws[WS_EEX + i];
  for (int i = t; i < MIXc * PHc; i += 256) sEEY[i] = ws[WS_EEY + i];
  if (t < 64) sbias[t] = bias[t];
  for (int i = t; i < 12 * 64; i += 256) swv[i] = wv[i];
  if (t < 4 * NK) {  // 4 threads per k over 196 partials
    const int k = t >> 2, p = t & 3;
    const float* base = ws + WS_PART + (b * NK + k) * NCHUNK;
    float s = 0.f;
    for (int cc = p; cc < NCHUNK; cc += 4) s += base[cc];
    s += __shfl_xor(s, 1, 64);
    s += __shfl_xor(s, 2, 64);
    if (p == 0) sdninv[k] = 1.f / s;
  }
  __syncthreads();

  const int g = t >> 5, px = t & 31;
  const int n = c * 32 + px;
  const int fh = n / FWc, fw = n - fh * FWc;
  const int i0 = 2 * fh, j0 = 2 * fw;
  const float* xb = x + (size_t)b * 3 * HWc;
  const int co = i0 * Wc + j0;
  const float xc0 = xb[co], xc1 = xb[HWc + co], xc2 = xb[2 * HWc + co];
  const float q0 = xc0 * sCol[0] + xc1 * sCol[3] + xc2 * sCol[6];
  const float q1 = xc0 * sCol[1] + xc1 * sCol[4] + xc2 * sCol[7];
  const float q2 = xc0 * sCol[2] + xc1 * sCol[5] + xc2 * sCol[8];

  float T[12] = {0.f};  // [m*3+ci], static indexing only
#pragma unroll
  for (int it = 0; it < 7; ++it) {
    const int kk = g + 8 * it;
    if (kk < NK) {
      const int kh = kk / 7, kw = kk - 7 * kh;
      const int ir = i0 + kh - PADc, jc = j0 + kw - PADc;
      if ((unsigned)ir < (unsigned)Hc && (unsigned)jc < (unsigned)Wc) {
        float s = xc0 * (sCol[9 + kw] + sCol[30 + kh]) +
                  xc1 * (sCol[16 + kw] + sCol[37 + kh]) +
                  xc2 * (sCol[23 + kw] + sCol[44 + kh]);
        const int off = ir * Wc + jc;
        const float x0 = xb[off], x1 = xb[HWc + off], x2 = xb[2 * HWc + off];
        s += q0 * x0 + q1 * x1 + q2 * x2;
        const float e = __expf(s) * sdninv[kk];
        const int ii = i0 + kh, jj = j0 + kw;
        const float p0 = sEEX[jj] * sEEY[ii];
        const float p1 = sEEX[PWc + jj] * sEEY[PHc + ii];
        const float p2 = sEEX[2 * PWc + jj] * sEEY[2 * PHc + ii];
        const float p3 = sEEX[3 * PWc + jj] * sEEY[3 * PHc + ii];
        const float wgt = e * __builtin_amdgcn_rcpf(p0 + p1 + p2 + p3);
        const float a0 = wgt * p0, a1 = wgt * p1, a2 = wgt * p2, a3 = wgt * p3;
        T[0] += a0 * x0; T[1]  += a0 * x1; T[2]  += a0 * x2;
        T[3] += a1 * x0; T[4]  += a1 * x1; T[5]  += a1 * x2;
        T[6] += a2 * x0; T[7]  += a2 * x1; T[8]  += a2 * x2;
        T[9] += a3 * x0; T[10] += a3 * x1; T[11] += a3 * x2;
      }
    }
  }
#pragma unroll
  for (int j = 0; j < 12; ++j) sT[g][px][j] = T[j];
  __syncthreads();

  float Tm[12];
#pragma unroll
  for (int j = 0; j < 12; ++j) {
    float s = 0.f;
#pragma unroll
    for (int ww = 0; ww < 8; ++ww) s += sT[ww][px][j];
    Tm[j] = s;
  }
  float* ob = out + (size_t)b * COUTc * NN + n;
#pragma unroll
  for (int oo = 0; oo < 8; ++oo) {
    const int o = g * 8 + oo;
    float acc = sbias[o];
#pragma unroll
    for (int mc = 0; mc < 12; ++mc) acc += swv[mc * 64 + o] * Tm[mc];
    ob[(size_t)o * NN] = acc;
  }
}

extern "C" void kernel_launch(void* const* d_in, const int* in_sizes, int n_in,
                              void* d_out, int out_size, void* d_ws, size_t ws_size,
                              hipStream_t stream) {
  const float* x    = (const float*)d_in[0];
  const float* wq   = (const float*)d_in[1];
  const float* wk   = (const float*)d_in[2];
  const float* wv   = (const float*)d_in[3];
  const float* rx   = (const float*)d_in[4];
  const float* ry   = (const float*)d_in[5];
  const float* ex   = (const float*)d_in[6];
  const float* ey   = (const float*)d_in[7];
  const float* em   = (const float*)d_in[8];
  const float* bias = (const float*)d_in[9];
  float* out = (float*)d_out;
  float* ws  = (float*)d_ws;

  sam_stats<<<dim3(NCHUNK, 13, Bc), 256, 0, stream>>>(x, wq, wk, rx, ry, ex, ey,
                                                      em, ws);
  sam_out<<<dim3(NN / 32, Bc), 256, 0, stream>>>(x, wq, wk, rx, ry, wv, bias,
                                                 ws, out);
}

// Round 11
// 102.214 us; speedup vs baseline: 1.1668x; 1.1668x over previous
//
#include <hip/hip_runtime.h>
#include <math.h>

namespace {
constexpr int Bc = 2, Hc = 224, Wc = 224, HWc = Hc * Wc;
constexpr int COUTc = 64, KHc = 7, KWc = 7, PADc = 3;
constexpr int MIXc = 4, RELc = 32;
constexpr int PHc = 230, PWc = 230;
constexpr int FHc = 112, FWc = 112, NN = FHc * FWc;   // 12544 = 196*64
constexpr int NK = KHc * KWc;                         // 49
// ws float offsets
constexpr int WS_EEX = 0;                             // [4][230] exp(ex.em)
constexpr int WS_EEY = WS_EEX + MIXc * PWc;           // [4][230] exp(ey.em)
constexpr int WS_COL = WS_EEY + MIXc * PHc;           // M[9], Rx[21], Ry[21]
constexpr int WS_ACC = 1920;                          // [B][49] slots, 16-float (64B) padded
}

// ---- K0: mixture-softmax tables + collapsed weights + zero accumulators.
__global__ __launch_bounds__(256) void sam_k0(
    const float* __restrict__ ex, const float* __restrict__ ey,
    const float* __restrict__ em, const float* __restrict__ wq,
    const float* __restrict__ wk, const float* __restrict__ rx,
    const float* __restrict__ ry, float* __restrict__ ws) {
  const int idx = blockIdx.x * 256 + threadIdx.x;
  if (idx < Bc * NK) ws[WS_ACC + idx * 16] = 0.f;  // zero softmax denominators

  constexpr int half = MIXc * PWc;
  if (idx < 2 * half) {
    const int which = idx >= half;
    const int r = which ? idx - half : idx;
    const int m = r / PWc, j = r % PWc;
    float s = 0.f;
#pragma unroll 8
    for (int c = 0; c < COUTc; ++c)
      s += (which ? ey[c * PHc + j] : ex[c * PWc + j]) * em[m * COUTc + c];
    ws[idx] = expf(s);
  }

  const int u = idx - 2 * half;
  if (u >= 0 && u < 51) {
    float s = 0.f;
    if (u < 9) {                      // M[cj*3+ci] = sum_o wq[cj,o]*wk[ci,o]
      const int cj = u / 3, ci = u % 3;
#pragma unroll 8
      for (int o = 0; o < COUTc; ++o) s += wq[cj * COUTc + o] * wk[ci * COUTc + o];
    } else if (u < 30) {              // Rx[cj*7+kw] = sum_{o<32} wq[cj,o]*rx[o,kw]
      const int v = u - 9, cj = v / 7, kw = v % 7;
#pragma unroll 8
      for (int o = 0; o < RELc; ++o) s += wq[cj * COUTc + o] * rx[o * KWc + kw];
    } else {                          // Ry[cj*7+kh] = sum_{o<32} wq[cj,32+o]*ry[o,kh]
      const int v = u - 30, cj = v / 7, kh = v % 7;
#pragma unroll 8
      for (int o = 0; o < RELc; ++o) s += wq[cj * COUTc + RELc + o] * ry[o * KHc + kh];
    }
    ws[WS_COL + u] = s;
  }
}

// ---- K1: global-softmax denominators. One wave = one k over 64 positions.
// grid (NN/64=196, ceil(49/4)=13, B), block 256.
__global__ __launch_bounds__(256) void sam_stats(const float* __restrict__ x,
                                                 float* __restrict__ ws) {
  __shared__ float sCol[51];
  const int t = threadIdx.x;
  if (t < 51) sCol[t] = ws[WS_COL + t];
  __syncthreads();

  const int w = t >> 6, lane = t & 63;
  const int k = blockIdx.y * 4 + w;
  if (k >= NK) return;
  const int b = blockIdx.z;
  const int kh = k / 7, kw = k - 7 * kh;
  const int n = blockIdx.x * 64 + lane;
  const int fh = n / FWc, fw = n - fh * FWc;
  const int i0 = 2 * fh, j0 = 2 * fw;
  const float* xb = x + (size_t)b * 3 * HWc;
  const int co = i0 * Wc + j0;
  const float xc0 = xb[co], xc1 = xb[HWc + co], xc2 = xb[2 * HWc + co];
  const float* M = sCol;
  const float* Rx = sCol + 9;
  const float* Ry = sCol + 30;

  float s = xc0 * (Rx[kw] + Ry[kh]) + xc1 * (Rx[7 + kw] + Ry[7 + kh]) +
            xc2 * (Rx[14 + kw] + Ry[14 + kh]);
  const int ir = i0 + kh - PADc, jc = j0 + kw - PADc;
  if ((unsigned)ir < (unsigned)Hc && (unsigned)jc < (unsigned)Wc) {
    const float q0 = xc0 * M[0] + xc1 * M[3] + xc2 * M[6];
    const float q1 = xc0 * M[1] + xc1 * M[4] + xc2 * M[7];
    const float q2 = xc0 * M[2] + xc1 * M[5] + xc2 * M[8];
    const int off = ir * Wc + jc;
    s += q0 * xb[off] + q1 * xb[HWc + off] + q2 * xb[2 * HWc + off];
  }
  float e = expf(s);
#pragma unroll
  for (int m2 = 32; m2; m2 >>= 1) e += __shfl_xor(e, m2, 64);
  if (lane == 0) atomicAdd(ws + WS_ACC + ((size_t)b * NK + k) * 16, e);
}

// ---- K2: output. Block = 512 threads = 64 pixels x 8 tap-groups.
// grid (NN/64=196, B).
__global__ __launch_bounds__(512) void sam_out(
    const float* __restrict__ x, const float* __restrict__ wv,
    const float* __restrict__ bias, const float* __restrict__ ws,
    float* __restrict__ out) {
  __shared__ float sCol[51];
  __shared__ float sdninv[NK];
  __shared__ float swv[12 * 64];
  __shared__ float sbias[64];
  __shared__ float sT[8][64][13];  // stride 13 -> conflict-light

  const int t = threadIdx.x;
  const int b = blockIdx.y;
  if (t < 51) sCol[t] = ws[WS_COL + t];
  if (t < NK) sdninv[t] = 1.f / ws[WS_ACC + ((size_t)b * NK + t) * 16];
  if (t < 64) sbias[t] = bias[t];
  for (int i = t; i < 12 * 64; i += 512) swv[i] = wv[i];
  __syncthreads();

  const int w = t >> 6, l = t & 63;
  const int n = blockIdx.x * 64 + l;
  const int fh = n / FWc, fw = n - fh * FWc;
  const int i0 = 2 * fh, j0 = 2 * fw;
  const float* xb = x + (size_t)b * 3 * HWc;
  const int co = i0 * Wc + j0;
  const float xc0 = xb[co], xc1 = xb[HWc + co], xc2 = xb[2 * HWc + co];
  const float* M = sCol;
  const float* Rx = sCol + 9;
  const float* Ry = sCol + 30;
  const float q0 = xc0 * M[0] + xc1 * M[3] + xc2 * M[6];
  const float q1 = xc0 * M[1] + xc1 * M[4] + xc2 * M[7];
  const float q2 = xc0 * M[2] + xc1 * M[5] + xc2 * M[8];
  float rlx[7], rly[7];
#pragma unroll
  for (int kw = 0; kw < 7; ++kw)
    rlx[kw] = xc0 * Rx[kw] + xc1 * Rx[7 + kw] + xc2 * Rx[14 + kw];
#pragma unroll
  for (int kh = 0; kh < 7; ++kh)
    rly[kh] = xc0 * Ry[kh] + xc1 * Ry[7 + kh] + xc2 * Ry[14 + kh];

  const float* eEX = ws + WS_EEX;
  const float* eEY = ws + WS_EEY;

  float T[12] = {0.f};  // [m*3+ci]
#pragma unroll 1
  for (int kk = w; kk < NK; kk += 8) {
    const int kh = kk / 7, kw = kk - 7 * kh;
    const int ir = i0 + kh - PADc, jc = j0 + kw - PADc;
    if ((unsigned)ir >= (unsigned)Hc || (unsigned)jc >= (unsigned)Wc) continue;
    float s = rlx[kw] + rly[kh];
    const int off = ir * Wc + jc;
    const float x0 = xb[off], x1 = xb[HWc + off], x2 = xb[2 * HWc + off];
    s += q0 * x0 + q1 * x1 + q2 * x2;
    const float e = expf(s) * sdninv[kk];
    const int ii = i0 + kh, jj = j0 + kw;
    const float p0 = eEX[jj] * eEY[ii];
    const float p1 = eEX[PWc + jj] * eEY[PHc + ii];
    const float p2 = eEX[2 * PWc + jj] * eEY[2 * PHc + ii];
    const float p3 = eEX[3 * PWc + jj] * eEY[3 * PHc + ii];
    const float wgt = e / (p0 + p1 + p2 + p3);
    const float a0 = wgt * p0, a1 = wgt * p1, a2 = wgt * p2, a3 = wgt * p3;
    T[0] += a0 * x0; T[1]  += a0 * x1; T[2]  += a0 * x2;
    T[3] += a1 * x0; T[4]  += a1 * x1; T[5]  += a1 * x2;
    T[6] += a2 * x0; T[7]  += a2 * x1; T[8]  += a2 * x2;
    T[9] += a3 * x0; T[10] += a3 * x1; T[11] += a3 * x2;
  }
#pragma unroll
  for (int j = 0; j < 12; ++j) sT[w][l][j] = T[j];
  __syncthreads();

  // Reduce 8 partials and project to 64 output channels (8 o's per thread).
  float Tm[12];
#pragma unroll
  for (int j = 0; j < 12; ++j) {
    float s = 0.f;
#pragma unroll
    for (int ww = 0; ww < 8; ++ww) s += sT[ww][l][j];
    Tm[j] = s;
  }
  float* ob = out + (size_t)b * COUTc * NN + n;
#pragma unroll
  for (int oo = 0; oo < 8; ++oo) {
    const int o = w * 8 + oo;
    float acc = sbias[o];
#pragma unroll
    for (int mc = 0; mc < 12; ++mc) acc += swv[mc * 64 + o] * Tm[mc];
    ob[(size_t)o * NN] = acc;
  }
}

extern "C" void kernel_launch(void* const* d_in, const int* in_sizes, int n_in,
                              void* d_out, int out_size, void* d_ws, size_t ws_size,
                              hipStream_t stream) {
  const float* x    = (const float*)d_in[0];
  const float* wq   = (const float*)d_in[1];
  const float* wk   = (const float*)d_in[2];
  const float* wv   = (const float*)d_in[3];
  const float* rx   = (const float*)d_in[4];
  const float* ry   = (const float*)d_in[5];
  const float* ex   = (const float*)d_in[6];
  const float* ey   = (const float*)d_in[7];
  const float* em   = (const float*)d_in[8];
  const float* bias = (const float*)d_in[9];
  float* out = (float*)d_out;
  float* ws  = (float*)d_ws;

  sam_k0<<<dim3(8), 256, 0, stream>>>(ex, ey, em, wq, wk, rx, ry, ws);
  sam_stats<<<dim3(NN / 64, (NK + 3) / 4, Bc), 256, 0, stream>>>(x, ws);
  sam_out<<<dim3(NN / 64, Bc), 512, 0, stream>>>(x, wv, bias, ws, out);
}

// Round 12
// 100.073 us; speedup vs baseline: 1.1917x; 1.0214x over previous
//
#include <hip/hip_runtime.h>
#include <math.h>

namespace {
constexpr int Bc = 2, Hc = 224, Wc = 224, HWc = Hc * Wc;
constexpr int COUTc = 64, KHc = 7, KWc = 7, PADc = 3;
constexpr int MIXc = 4, RELc = 32;
constexpr int PHc = 230, PWc = 230;
constexpr int FHc = 112, FWc = 112, NN = FHc * FWc;   // 12544 = 196*64
constexpr int NK = KHc * KWc;                         // 49
// ws float offsets
constexpr int WS_EEX = 0;                             // [4][230] exp(ex.em)
constexpr int WS_EEY = WS_EEX + MIXc * PWc;           // [4][230] exp(ey.em)
constexpr int WS_COL = WS_EEY + MIXc * PHc;           // M[9], Rx[21], Ry[21]
constexpr int WS_ACC = 1920;                          // [B][49] slots, 16-float (64B) padded
}

// ---- K0: mixture-softmax tables + collapsed weights + zero accumulators.
__global__ __launch_bounds__(256) void sam_k0(
    const float* __restrict__ ex, const float* __restrict__ ey,
    const float* __restrict__ em, const float* __restrict__ wq,
    const float* __restrict__ wk, const float* __restrict__ rx,
    const float* __restrict__ ry, float* __restrict__ ws) {
  const int idx = blockIdx.x * 256 + threadIdx.x;
  if (idx < Bc * NK) ws[WS_ACC + idx * 16] = 0.f;  // zero softmax denominators

  constexpr int half = MIXc * PWc;
  if (idx < 2 * half) {
    const int which = idx >= half;
    const int r = which ? idx - half : idx;
    const int m = r / PWc, j = r % PWc;
    float s = 0.f;
#pragma unroll 8
    for (int c = 0; c < COUTc; ++c)
      s += (which ? ey[c * PHc + j] : ex[c * PWc + j]) * em[m * COUTc + c];
    ws[idx] = __expf(s);
  }

  const int u = idx - 2 * half;
  if (u >= 0 && u < 51) {
    float s = 0.f;
    if (u < 9) {                      // M[cj*3+ci] = sum_o wq[cj,o]*wk[ci,o]
      const int cj = u / 3, ci = u % 3;
#pragma unroll 8
      for (int o = 0; o < COUTc; ++o) s += wq[cj * COUTc + o] * wk[ci * COUTc + o];
    } else if (u < 30) {              // Rx[cj*7+kw] = sum_{o<32} wq[cj,o]*rx[o,kw]
      const int v = u - 9, cj = v / 7, kw = v % 7;
#pragma unroll 8
      for (int o = 0; o < RELc; ++o) s += wq[cj * COUTc + o] * rx[o * KWc + kw];
    } else {                          // Ry[cj*7+kh] = sum_{o<32} wq[cj,32+o]*ry[o,kh]
      const int v = u - 30, cj = v / 7, kh = v % 7;
#pragma unroll 8
      for (int o = 0; o < RELc; ++o) s += wq[cj * COUTc + RELc + o] * ry[o * KHc + kh];
    }
    ws[WS_COL + u] = s;
  }
}

// ---- K1: global-softmax denominators. One wave = one k over 64 positions.
// grid (NN/64=196, ceil(49/4)=13, B), block 256.
__global__ __launch_bounds__(256) void sam_stats(const float* __restrict__ x,
                                                 float* __restrict__ ws) {
  __shared__ float sCol[51];
  const int t = threadIdx.x;
  if (t < 51) sCol[t] = ws[WS_COL + t];
  __syncthreads();

  const int w = t >> 6, lane = t & 63;
  const int k = blockIdx.y * 4 + w;
  if (k >= NK) return;
  const int b = blockIdx.z;
  const int kh = k / 7, kw = k - 7 * kh;
  const int n = blockIdx.x * 64 + lane;
  const int fh = n / FWc, fw = n - fh * FWc;
  const int i0 = 2 * fh, j0 = 2 * fw;
  const float* xb = x + (size_t)b * 3 * HWc;
  const int co = i0 * Wc + j0;
  const float xc0 = xb[co], xc1 = xb[HWc + co], xc2 = xb[2 * HWc + co];
  const float* M = sCol;
  const float* Rx = sCol + 9;
  const float* Ry = sCol + 30;

  float s = xc0 * (Rx[kw] + Ry[kh]) + xc1 * (Rx[7 + kw] + Ry[7 + kh]) +
            xc2 * (Rx[14 + kw] + Ry[14 + kh]);
  const int ir = i0 + kh - PADc, jc = j0 + kw - PADc;
  if ((unsigned)ir < (unsigned)Hc && (unsigned)jc < (unsigned)Wc) {
    const float q0 = xc0 * M[0] + xc1 * M[3] + xc2 * M[6];
    const float q1 = xc0 * M[1] + xc1 * M[4] + xc2 * M[7];
    const float q2 = xc0 * M[2] + xc1 * M[5] + xc2 * M[8];
    const int off = ir * Wc + jc;
    s += q0 * xb[off] + q1 * xb[HWc + off] + q2 * xb[2 * HWc + off];
  }
  float e = __expf(s);
#pragma unroll
  for (int m2 = 32; m2; m2 >>= 1) e += __shfl_xor(e, m2, 64);
  if (lane == 0) atomicAdd(ws + WS_ACC + ((size_t)b * NK + k) * 16, e);
}

// ---- K2: output. Block = 512 threads = 64 pixels x 8 tap-groups.
// grid (NN/64=196, B).
__global__ __launch_bounds__(512) void sam_out(
    const float* __restrict__ x, const float* __restrict__ wv,
    const float* __restrict__ bias, const float* __restrict__ ws,
    float* __restrict__ out) {
  __shared__ float sCol[51];
  __shared__ float sdninv[NK];
  __shared__ float swv[12 * 64];
  __shared__ float sbias[64];
  __shared__ float sEEX[MIXc * PWc];
  __shared__ float sEEY[MIXc * PHc];
  __shared__ float sT[8][64][13];  // stride 13 -> conflict-light

  const int t = threadIdx.x;
  const int b = blockIdx.y;
  if (t < 51) sCol[t] = ws[WS_COL + t];
  if (t < NK) sdninv[t] = 1.f / ws[WS_ACC + ((size_t)b * NK + t) * 16];
  if (t < 64) sbias[t] = bias[t];
  for (int i = t; i < 12 * 64; i += 512) swv[i] = wv[i];
  for (int i = t; i < MIXc * PWc; i += 512) sEEX[i] = ws[WS_EEX + i];
  for (int i = t; i < MIXc * PHc; i += 512) sEEY[i] = ws[WS_EEY + i];
  __syncthreads();

  const int w = t >> 6, l = t & 63;
  const int n = blockIdx.x * 64 + l;
  const int fh = n / FWc, fw = n - fh * FWc;
  const int i0 = 2 * fh, j0 = 2 * fw;
  const float* xb = x + (size_t)b * 3 * HWc;
  const int co = i0 * Wc + j0;
  const float xc0 = xb[co], xc1 = xb[HWc + co], xc2 = xb[2 * HWc + co];
  const float q0 = xc0 * sCol[0] + xc1 * sCol[3] + xc2 * sCol[6];
  const float q1 = xc0 * sCol[1] + xc1 * sCol[4] + xc2 * sCol[7];
  const float q2 = xc0 * sCol[2] + xc1 * sCol[5] + xc2 * sCol[8];

  float T[12] = {0.f};  // [m*3+ci], static indexing only
#pragma unroll 1
  for (int kk = w; kk < NK; kk += 8) {
    const int kh = kk / 7, kw = kk - 7 * kh;
    const int ir = i0 + kh - PADc, jc = j0 + kw - PADc;
    if ((unsigned)ir >= (unsigned)Hc || (unsigned)jc >= (unsigned)Wc) continue;
    // score terms straight from LDS (runtime-index safe; no scratch arrays)
    float s = xc0 * (sCol[9 + kw] + sCol[30 + kh]) +
              xc1 * (sCol[16 + kw] + sCol[37 + kh]) +
              xc2 * (sCol[23 + kw] + sCol[44 + kh]);
    const int off = ir * Wc + jc;
    const float x0 = xb[off], x1 = xb[HWc + off], x2 = xb[2 * HWc + off];
    s += q0 * x0 + q1 * x1 + q2 * x2;
    const float e = __expf(s) * sdninv[kk];
    const int ii = i0 + kh, jj = j0 + kw;
    const float p0 = sEEX[jj] * sEEY[ii];
    const float p1 = sEEX[PWc + jj] * sEEY[PHc + ii];
    const float p2 = sEEX[2 * PWc + jj] * sEEY[2 * PHc + ii];
    const float p3 = sEEX[3 * PWc + jj] * sEEY[3 * PHc + ii];
    const float wgt = e * __builtin_amdgcn_rcpf(p0 + p1 + p2 + p3);
    const float a0 = wgt * p0, a1 = wgt * p1, a2 = wgt * p2, a3 = wgt * p3;
    T[0] += a0 * x0; T[1]  += a0 * x1; T[2]  += a0 * x2;
    T[3] += a1 * x0; T[4]  += a1 * x1; T[5]  += a1 * x2;
    T[6] += a2 * x0; T[7]  += a2 * x1; T[8]  += a2 * x2;
    T[9] += a3 * x0; T[10] += a3 * x1; T[11] += a3 * x2;
  }
#pragma unroll
  for (int j = 0; j < 12; ++j) sT[w][l][j] = T[j];
  __syncthreads();

  // Reduce 8 partials and project to 64 output channels (8 o's per thread).
  float Tm[12];
#pragma unroll
  for (int j = 0; j < 12; ++j) {
    float s = 0.f;
#pragma unroll
    for (int ww = 0; ww < 8; ++ww) s += sT[ww][l][j];
    Tm[j] = s;
  }
  float* ob = out + (size_t)b * COUTc * NN + n;
#pragma unroll
  for (int oo = 0; oo < 8; ++oo) {
    const int o = w * 8 + oo;
    float acc = sbias[o];
#pragma unroll
    for (int mc = 0; mc < 12; ++mc) acc += swv[mc * 64 + o] * Tm[mc];
    ob[(size_t)o * NN] = acc;
  }
}

extern "C" void kernel_launch(void* const* d_in, const int* in_sizes, int n_in,
                              void* d_out, int out_size, void* d_ws, size_t ws_size,
                              hipStream_t stream) {
  const float* x    = (const float*)d_in[0];
  const float* wq   = (const float*)d_in[1];
  const float* wk   = (const float*)d_in[2];
  const float* wv   = (const float*)d_in[3];
  const float* rx   = (const float*)d_in[4];
  const float* ry   = (const float*)d_in[5];
  const float* ex   = (const float*)d_in[6];
  const float* ey   = (const float*)d_in[7];
  const float* em   = (const float*)d_in[8];
  const float* bias = (const float*)d_in[9];
  float* out = (float*)d_out;
  float* ws  = (float*)d_ws;

  sam_k0<<<dim3(8), 256, 0, stream>>>(ex, ey, em, wq, wk, rx, ry, ws);
  sam_stats<<<dim3(NN / 64, (NK + 3) / 4, Bc), 256, 0, stream>>>(x, ws);
  sam_out<<<dim3(NN / 64, Bc), 512, 0, stream>>>(x, wv, bias, ws, out);
}

// Round 13
// 96.108 us; speedup vs baseline: 1.2409x; 1.0413x over previous
//
#include <hip/hip_runtime.h>
#include <math.h>

namespace {
constexpr int Bc = 2, Hc = 224, Wc = 224, HWc = Hc * Wc;
constexpr int COUTc = 64, KHc = 7, KWc = 7, PADc = 3;
constexpr int MIXc = 4, RELc = 32;
constexpr int PHc = 230, PWc = 230;
constexpr int FHc = 112, FWc = 112, NN = FHc * FWc;   // 12544 = 196*64
constexpr int NK = KHc * KWc;                         // 49
// ws float offsets
constexpr int WS_EEX = 0;                             // [4][230] exp(ex.em)
constexpr int WS_EEY = WS_EEX + MIXc * PWc;           // [4][230] exp(ey.em)
constexpr int WS_COL = WS_EEY + MIXc * PHc;           // M[9], Rx[21], Ry[21]
constexpr int WS_ACC = 1920;                          // [B][49] slots, 16-float (64B) padded
}

// ---- K0: mixture-softmax tables + collapsed weights + zero accumulators.
__global__ __launch_bounds__(256) void sam_k0(
    const float* __restrict__ ex, const float* __restrict__ ey,
    const float* __restrict__ em, const float* __restrict__ wq,
    const float* __restrict__ wk, const float* __restrict__ rx,
    const float* __restrict__ ry, float* __restrict__ ws) {
  const int idx = blockIdx.x * 256 + threadIdx.x;
  if (idx < Bc * NK) ws[WS_ACC + idx * 16] = 0.f;  // zero softmax denominators

  constexpr int half = MIXc * PWc;
  if (idx < 2 * half) {
    const int which = idx >= half;
    const int r = which ? idx - half : idx;
    const int m = r / PWc, j = r % PWc;
    float s = 0.f;
#pragma unroll 8
    for (int c = 0; c < COUTc; ++c)
      s += (which ? ey[c * PHc + j] : ex[c * PWc + j]) * em[m * COUTc + c];
    ws[idx] = __expf(s);
  }

  const int u = idx - 2 * half;
  if (u >= 0 && u < 51) {
    float s = 0.f;
    if (u < 9) {                      // M[cj*3+ci] = sum_o wq[cj,o]*wk[ci,o]
      const int cj = u / 3, ci = u % 3;
#pragma unroll 8
      for (int o = 0; o < COUTc; ++o) s += wq[cj * COUTc + o] * wk[ci * COUTc + o];
    } else if (u < 30) {              // Rx[cj*7+kw] = sum_{o<32} wq[cj,o]*rx[o,kw]
      const int v = u - 9, cj = v / 7, kw = v % 7;
#pragma unroll 8
      for (int o = 0; o < RELc; ++o) s += wq[cj * COUTc + o] * rx[o * KWc + kw];
    } else {                          // Ry[cj*7+kh] = sum_{o<32} wq[cj,32+o]*ry[o,kh]
      const int v = u - 30, cj = v / 7, kh = v % 7;
#pragma unroll 8
      for (int o = 0; o < RELc; ++o) s += wq[cj * COUTc + RELc + o] * ry[o * KHc + kh];
    }
    ws[WS_COL + u] = s;
  }
}

// ---- K1: global-softmax denominators. One wave = one k over 128 positions.
// grid (NN/128=98, ceil(49/4)=13, B), block 256.
__global__ __launch_bounds__(256) void sam_stats(const float* __restrict__ x,
                                                 float* __restrict__ ws) {
  __shared__ float sCol[51];
  const int t = threadIdx.x;
  if (t < 51) sCol[t] = ws[WS_COL + t];
  __syncthreads();

  const int w = t >> 6, lane = t & 63;
  const int k = blockIdx.y * 4 + w;
  if (k >= NK) return;
  const int b = blockIdx.z;
  const int kh = k / 7, kw = k - 7 * kh;
  const float* xb = x + (size_t)b * 3 * HWc;
  const float r0 = sCol[9 + kw] + sCol[30 + kh];
  const float r1 = sCol[16 + kw] + sCol[37 + kh];
  const float r2 = sCol[23 + kw] + sCol[44 + kh];

  float esum = 0.f;
#pragma unroll
  for (int hlf = 0; hlf < 2; ++hlf) {
    const int n = blockIdx.x * 128 + hlf * 64 + lane;
    const int fh = n / FWc, fw = n - fh * FWc;
    const int i0 = 2 * fh, j0 = 2 * fw;
    const int co = i0 * Wc + j0;
    const float xc0 = xb[co], xc1 = xb[HWc + co], xc2 = xb[2 * HWc + co];
    float s = xc0 * r0 + xc1 * r1 + xc2 * r2;
    const int ir = i0 + kh - PADc, jc = j0 + kw - PADc;
    if ((unsigned)ir < (unsigned)Hc && (unsigned)jc < (unsigned)Wc) {
      const float q0 = xc0 * sCol[0] + xc1 * sCol[3] + xc2 * sCol[6];
      const float q1 = xc0 * sCol[1] + xc1 * sCol[4] + xc2 * sCol[7];
      const float q2 = xc0 * sCol[2] + xc1 * sCol[5] + xc2 * sCol[8];
      const int off = ir * Wc + jc;
      s += q0 * xb[off] + q1 * xb[HWc + off] + q2 * xb[2 * HWc + off];
    }
    esum += __expf(s);
  }
#pragma unroll
  for (int m2 = 32; m2; m2 >>= 1) esum += __shfl_xor(esum, m2, 64);
  if (lane == 0) atomicAdd(ws + WS_ACC + ((size_t)b * NK + k) * 16, esum);
}

// ---- K2: output. Block = 512 threads = 64 pixels x 8 tap-groups.
// grid (NN/64=196, B).
__global__ __launch_bounds__(512) void sam_out(
    const float* __restrict__ x, const float* __restrict__ wv,
    const float* __restrict__ bias, const float* __restrict__ ws,
    float* __restrict__ out) {
  __shared__ float sCol[51];
  __shared__ float sdninv[NK];
  __shared__ float swv[12 * 64];
  __shared__ float sbias[64];
  __shared__ float sEEX[MIXc * PWc];
  __shared__ float sEEY[MIXc * PHc];
  __shared__ float sT[8][64][13];  // stride 13 -> conflict-light

  const int t = threadIdx.x;
  const int b = blockIdx.y;
  if (t < 51) sCol[t] = ws[WS_COL + t];
  if (t < NK) sdninv[t] = 1.f / ws[WS_ACC + ((size_t)b * NK + t) * 16];
  if (t < 64) sbias[t] = bias[t];
  for (int i = t; i < 12 * 64; i += 512) swv[i] = wv[i];
  for (int i = t; i < MIXc * PWc; i += 512) sEEX[i] = ws[WS_EEX + i];
  for (int i = t; i < MIXc * PHc; i += 512) sEEY[i] = ws[WS_EEY + i];
  __syncthreads();

  const int w = t >> 6, l = t & 63;
  const int n = blockIdx.x * 64 + l;
  const int fh = n / FWc, fw = n - fh * FWc;
  const int i0 = 2 * fh, j0 = 2 * fw;
  const float* xb = x + (size_t)b * 3 * HWc;
  const int co = i0 * Wc + j0;
  const float xc0 = xb[co], xc1 = xb[HWc + co], xc2 = xb[2 * HWc + co];
  const float q0 = xc0 * sCol[0] + xc1 * sCol[3] + xc2 * sCol[6];
  const float q1 = xc0 * sCol[1] + xc1 * sCol[4] + xc2 * sCol[7];
  const float q2 = xc0 * sCol[2] + xc1 * sCol[5] + xc2 * sCol[8];

  float T[12] = {0.f};  // [m*3+ci], static indexing only
#pragma unroll 1
  for (int kk = w; kk < NK; kk += 8) {
    const int kh = kk / 7, kw = kk - 7 * kh;
    const int ir = i0 + kh - PADc, jc = j0 + kw - PADc;
    if ((unsigned)ir >= (unsigned)Hc || (unsigned)jc >= (unsigned)Wc) continue;
    // score terms straight from LDS (runtime-index safe; no scratch arrays)
    float s = xc0 * (sCol[9 + kw] + sCol[30 + kh]) +
              xc1 * (sCol[16 + kw] + sCol[37 + kh]) +
              xc2 * (sCol[23 + kw] + sCol[44 + kh]);
    const int off = ir * Wc + jc;
    const float x0 = xb[off], x1 = xb[HWc + off], x2 = xb[2 * HWc + off];
    s += q0 * x0 + q1 * x1 + q2 * x2;
    const float e = __expf(s) * sdninv[kk];
    const int ii = i0 + kh, jj = j0 + kw;
    const float p0 = sEEX[jj] * sEEY[ii];
    const float p1 = sEEX[PWc + jj] * sEEY[PHc + ii];
    const float p2 = sEEX[2 * PWc + jj] * sEEY[2 * PHc + ii];
    const float p3 = sEEX[3 * PWc + jj] * sEEY[3 * PHc + ii];
    const float wgt = e * __builtin_amdgcn_rcpf(p0 + p1 + p2 + p3);
    const float a0 = wgt * p0, a1 = wgt * p1, a2 = wgt * p2, a3 = wgt * p3;
    T[0] += a0 * x0; T[1]  += a0 * x1; T[2]  += a0 * x2;
    T[3] += a1 * x0; T[4]  += a1 * x1; T[5]  += a1 * x2;
    T[6] += a2 * x0; T[7]  += a2 * x1; T[8]  += a2 * x2;
    T[9] += a3 * x0; T[10] += a3 * x1; T[11] += a3 * x2;
  }
#pragma unroll
  for (int j = 0; j < 12; ++j) sT[w][l][j] = T[j];
  __syncthreads();

  // Reduce 8 partials and project to 64 output channels (8 o's per thread).
  float Tm[12];
#pragma unroll
  for (int j = 0; j < 12; ++j) {
    float s = 0.f;
#pragma unroll
    for (int ww = 0; ww < 8; ++ww) s += sT[ww][l][j];
    Tm[j] = s;
  }
  float* ob = out + (size_t)b * COUTc * NN + n;
#pragma unroll
  for (int oo = 0; oo < 8; ++oo) {
    const int o = w * 8 + oo;
    float acc = sbias[o];
#pragma unroll
    for (int mc = 0; mc < 12; ++mc) acc += swv[mc * 64 + o] * Tm[mc];
    ob[(size_t)o * NN] = acc;
  }
}

extern "C" void kernel_launch(void* const* d_in, const int* in_sizes, int n_in,
                              void* d_out, int out_size, void* d_ws, size_t ws_size,
                              hipStream_t stream) {
  const float* x    = (const float*)d_in[0];
  const float* wq   = (const float*)d_in[1];
  const float* wk   = (const float*)d_in[2];
  const float* wv   = (const float*)d_in[3];
  const float* rx   = (const float*)d_in[4];
  const float* ry   = (const float*)d_in[5];
  const float* ex   = (const float*)d_in[6];
  const float* ey   = (const float*)d_in[7];
  const float* em   = (const float*)d_in[8];
  const float* bias = (const float*)d_in[9];
  float* out = (float*)d_out;
  float* ws  = (float*)d_ws;

  sam_k0<<<dim3(8), 256, 0, stream>>>(ex, ey, em, wq, wk, rx, ry, ws);
  sam_stats<<<dim3(NN / 128, (NK + 3) / 4, Bc), 256, 0, stream>>>(x, ws);
  sam_out<<<dim3(NN / 64, Bc), 512, 0, stream>>>(x, wv, bias, ws, out);
}

// Round 14
// 94.569 us; speedup vs baseline: 1.2611x; 1.0163x over previous
//
#include <hip/hip_runtime.h>
#include <math.h>

namespace {
constexpr int Bc = 2, Hc = 224, Wc = 224, HWc = Hc * Wc;
constexpr int COUTc = 64, KHc = 7, KWc = 7, PADc = 3;
constexpr int MIXc = 4, RELc = 32;
constexpr int PHc = 230, PWc = 230;
constexpr int FHc = 112, FWc = 112, NN = FHc * FWc;   // 12544 = 196*64
constexpr int NK = KHc * KWc;                         // 49
// ws float offsets
constexpr int WS_EEX = 0;                             // [4][230] exp(ex.em)
constexpr int WS_EEY = WS_EEX + MIXc * PWc;           // [4][230] exp(ey.em)
constexpr int WS_COL = WS_EEY + MIXc * PHc;           // M[9], Rx[21], Ry[21]
constexpr int WS_ACC = 1920;                          // [B][49] slots, 16-float (64B) padded
}

// ---- K0: mixture-softmax tables + collapsed weights + zero accumulators.
__global__ __launch_bounds__(256) void sam_k0(
    const float* __restrict__ ex, const float* __restrict__ ey,
    const float* __restrict__ em, const float* __restrict__ wq,
    const float* __restrict__ wk, const float* __restrict__ rx,
    const float* __restrict__ ry, float* __restrict__ ws) {
  const int idx = blockIdx.x * 256 + threadIdx.x;
  if (idx < Bc * NK) ws[WS_ACC + idx * 16] = 0.f;  // zero softmax denominators

  constexpr int half = MIXc * PWc;
  if (idx < 2 * half) {
    const int which = idx >= half;
    const int r = which ? idx - half : idx;
    const int m = r / PWc, j = r % PWc;
    float s = 0.f;
#pragma unroll 8
    for (int c = 0; c < COUTc; ++c)
      s += (which ? ey[c * PHc + j] : ex[c * PWc + j]) * em[m * COUTc + c];
    ws[idx] = __expf(s);
  }

  const int u = idx - 2 * half;
  if (u >= 0 && u < 51) {
    float s = 0.f;
    if (u < 9) {                      // M[cj*3+ci] = sum_o wq[cj,o]*wk[ci,o]
      const int cj = u / 3, ci = u % 3;
#pragma unroll 8
      for (int o = 0; o < COUTc; ++o) s += wq[cj * COUTc + o] * wk[ci * COUTc + o];
    } else if (u < 30) {              // Rx[cj*7+kw] = sum_{o<32} wq[cj,o]*rx[o,kw]
      const int v = u - 9, cj = v / 7, kw = v % 7;
#pragma unroll 8
      for (int o = 0; o < RELc; ++o) s += wq[cj * COUTc + o] * rx[o * KWc + kw];
    } else {                          // Ry[cj*7+kh] = sum_{o<32} wq[cj,32+o]*ry[o,kh]
      const int v = u - 30, cj = v / 7, kh = v % 7;
#pragma unroll 8
      for (int o = 0; o < RELc; ++o) s += wq[cj * COUTc + RELc + o] * ry[o * KHc + kh];
    }
    ws[WS_COL + u] = s;
  }
}

// ---- K1: global-softmax denominators. One wave = one k over 256 positions.
// grid (NN/256=49, ceil(49/4)=13, B), block 256.
__global__ __launch_bounds__(256) void sam_stats(const float* __restrict__ x,
                                                 float* __restrict__ ws) {
  __shared__ float sCol[51];
  const int t = threadIdx.x;
  if (t < 51) sCol[t] = ws[WS_COL + t];
  __syncthreads();

  const int w = t >> 6, lane = t & 63;
  const int k = blockIdx.y * 4 + w;
  if (k >= NK) return;
  const int b = blockIdx.z;
  const int kh = k / 7, kw = k - 7 * kh;
  const float* xb = x + (size_t)b * 3 * HWc;
  const float r0 = sCol[9 + kw] + sCol[30 + kh];
  const float r1 = sCol[16 + kw] + sCol[37 + kh];
  const float r2 = sCol[23 + kw] + sCol[44 + kh];

  float esum = 0.f;
#pragma unroll
  for (int hlf = 0; hlf < 4; ++hlf) {
    const int n = blockIdx.x * 256 + hlf * 64 + lane;
    const int fh = n / FWc, fw = n - fh * FWc;
    const int i0 = 2 * fh, j0 = 2 * fw;
    const int co = i0 * Wc + j0;
    const float xc0 = xb[co], xc1 = xb[HWc + co], xc2 = xb[2 * HWc + co];
    float s = xc0 * r0 + xc1 * r1 + xc2 * r2;
    const int ir = i0 + kh - PADc, jc = j0 + kw - PADc;
    if ((unsigned)ir < (unsigned)Hc && (unsigned)jc < (unsigned)Wc) {
      const float q0 = xc0 * sCol[0] + xc1 * sCol[3] + xc2 * sCol[6];
      const float q1 = xc0 * sCol[1] + xc1 * sCol[4] + xc2 * sCol[7];
      const float q2 = xc0 * sCol[2] + xc1 * sCol[5] + xc2 * sCol[8];
      const int off = ir * Wc + jc;
      s += q0 * xb[off] + q1 * xb[HWc + off] + q2 * xb[2 * HWc + off];
    }
    esum += __expf(s);
  }
#pragma unroll
  for (int m2 = 32; m2; m2 >>= 1) esum += __shfl_xor(esum, m2, 64);
  if (lane == 0) atomicAdd(ws + WS_ACC + ((size_t)b * NK + k) * 16, esum);
}

// ---- K2: output. Block = 512 threads = 64 pixels x 8 tap-groups, 2 passes.
// grid (NN/128=98, B).
__global__ __launch_bounds__(512) void sam_out(
    const float* __restrict__ x, const float* __restrict__ wv,
    const float* __restrict__ bias, const float* __restrict__ ws,
    float* __restrict__ out) {
  __shared__ float sCol[51];
  __shared__ float sdninv[NK];
  __shared__ float swv[12 * 64];
  __shared__ float sbias[64];
  __shared__ float sEEX[MIXc * PWc];
  __shared__ float sEEY[MIXc * PHc];
  __shared__ float sT[8][64][13];  // stride 13 -> conflict-light

  const int t = threadIdx.x;
  const int b = blockIdx.y;
  if (t < 51) sCol[t] = ws[WS_COL + t];
  if (t < NK) sdninv[t] = 1.f / ws[WS_ACC + ((size_t)b * NK + t) * 16];
  if (t < 64) sbias[t] = bias[t];
  for (int i = t; i < 12 * 64; i += 512) swv[i] = wv[i];
  for (int i = t; i < MIXc * PWc; i += 512) sEEX[i] = ws[WS_EEX + i];
  for (int i = t; i < MIXc * PHc; i += 512) sEEY[i] = ws[WS_EEY + i];

  const int w = t >> 6, l = t & 63;
  const float* xb = x + (size_t)b * 3 * HWc;

#pragma unroll 1
  for (int pass = 0; pass < 2; ++pass) {
    const int n = blockIdx.x * 128 + pass * 64 + l;
    const int fh = n / FWc, fw = n - fh * FWc;
    const int i0 = 2 * fh, j0 = 2 * fw;
    const int co = i0 * Wc + j0;
    __syncthreads();  // pass 0: prologue barrier; pass 1: sT reuse guard
    const float xc0 = xb[co], xc1 = xb[HWc + co], xc2 = xb[2 * HWc + co];
    const float q0 = xc0 * sCol[0] + xc1 * sCol[3] + xc2 * sCol[6];
    const float q1 = xc0 * sCol[1] + xc1 * sCol[4] + xc2 * sCol[7];
    const float q2 = xc0 * sCol[2] + xc1 * sCol[5] + xc2 * sCol[8];

    float T[12] = {0.f};  // [m*3+ci], static indexing only
#pragma unroll 1
    for (int kk = w; kk < NK; kk += 8) {
      const int kh = kk / 7, kw = kk - 7 * kh;
      const int ir = i0 + kh - PADc, jc = j0 + kw - PADc;
      if ((unsigned)ir >= (unsigned)Hc || (unsigned)jc >= (unsigned)Wc) continue;
      float s = xc0 * (sCol[9 + kw] + sCol[30 + kh]) +
                xc1 * (sCol[16 + kw] + sCol[37 + kh]) +
                xc2 * (sCol[23 + kw] + sCol[44 + kh]);
      const int off = ir * Wc + jc;
      const float x0 = xb[off], x1 = xb[HWc + off], x2 = xb[2 * HWc + off];
      s += q0 * x0 + q1 * x1 + q2 * x2;
      const float e = __expf(s) * sdninv[kk];
      const int ii = i0 + kh, jj = j0 + kw;
      const float p0 = sEEX[jj] * sEEY[ii];
      const float p1 = sEEX[PWc + jj] * sEEY[PHc + ii];
      const float p2 = sEEX[2 * PWc + jj] * sEEY[2 * PHc + ii];
      const float p3 = sEEX[3 * PWc + jj] * sEEY[3 * PHc + ii];
      const float wgt = e * __builtin_amdgcn_rcpf(p0 + p1 + p2 + p3);
      const float a0 = wgt * p0, a1 = wgt * p1, a2 = wgt * p2, a3 = wgt * p3;
      T[0] += a0 * x0; T[1]  += a0 * x1; T[2]  += a0 * x2;
      T[3] += a1 * x0; T[4]  += a1 * x1; T[5]  += a1 * x2;
      T[6] += a2 * x0; T[7]  += a2 * x1; T[8]  += a2 * x2;
      T[9] += a3 * x0; T[10] += a3 * x1; T[11] += a3 * x2;
    }
#pragma unroll
    for (int j = 0; j < 12; ++j) sT[w][l][j] = T[j];
    __syncthreads();

    // Reduce 8 partials and project to 64 output channels (8 o's per thread).
    float Tm[12];
#pragma unroll
    for (int j = 0; j < 12; ++j) {
      float s = 0.f;
#pragma unroll
      for (int ww = 0; ww < 8; ++ww) s += sT[ww][l][j];
      Tm[j] = s;
    }
    float* ob = out + (size_t)b * COUTc * NN + n;
#pragma unroll
    for (int oo = 0; oo < 8; ++oo) {
      const int o = w * 8 + oo;
      float acc = sbias[o];
#pragma unroll
      for (int mc = 0; mc < 12; ++mc) acc += swv[mc * 64 + o] * Tm[mc];
      ob[(size_t)o * NN] = acc;
    }
  }
}

extern "C" void kernel_launch(void* const* d_in, const int* in_sizes, int n_in,
                              void* d_out, int out_size, void* d_ws, size_t ws_size,
                              hipStream_t stream) {
  const float* x    = (const float*)d_in[0];
  const float* wq   = (const float*)d_in[1];
  const float* wk   = (const float*)d_in[2];
  const float* wv   = (const float*)d_in[3];
  const float* rx   = (const float*)d_in[4];
  const float* ry   = (const float*)d_in[5];
  const float* ex   = (const float*)d_in[6];
  const float* ey   = (const float*)d_in[7];
  const float* em   = (const float*)d_in[8];
  const float* bias = (const float*)d_in[9];
  float* out = (float*)d_out;
  float* ws  = (float*)d_ws;

  sam_k0<<<dim3(8), 256, 0, stream>>>(ex, ey, em, wq, wk, rx, ry, ws);
  sam_stats<<<dim3(NN / 256, (NK + 3) / 4, Bc), 256, 0, stream>>>(x, ws);
  sam_out<<<dim3(NN / 128, Bc), 512, 0, stream>>>(x, wv, bias, ws, out);
}